// Round 2
// baseline (346.740 us; speedup 1.0000x reference)
//
#include <hip/hip_runtime.h>
#include <stdint.h>

typedef unsigned short u16;
typedef unsigned int   u32;
typedef __attribute__((ext_vector_type(8))) short  short8;   // 8 x bf16 (4 VGPRs)
typedef __attribute__((ext_vector_type(4))) float  floatx4;  // MFMA acc

__device__ __forceinline__ u16 f32_to_bf16(float f) {
  u32 u = __builtin_bit_cast(u32, f);
  u = (u + 0x7fffu + ((u >> 16) & 1u)) >> 16;
  return (u16)u;
}
__device__ __forceinline__ float bf16_to_f32(u16 h) {
  u32 u = ((u32)h) << 16;
  return __builtin_bit_cast(float, u);
}
__device__ __forceinline__ u32 pack2(float a, float b) {
  return (u32)f32_to_bf16(a) | ((u32)f32_to_bf16(b) << 16);
}

// async global->LDS, 16B per lane. LDS dst = wave-uniform base + lane*16.
__device__ __forceinline__ void load_lds16(const u16* g, u16* l) {
  auto gp = (const __attribute__((address_space(1))) u32*)(uintptr_t)g;
  auto lp = (__attribute__((address_space(3))) u32*)(u32)(uintptr_t)l;
  __builtin_amdgcn_global_load_lds(gp, lp, 16, 0, 0);
}

// ---------------------------------------------------------------------------
// K1: fused QKV 1x1 conv + patch-token layout.
// Layout (verified, matches reference reshape semantics):
//   row(w,h) = ((h>>3)&1)*64 + (w&7)*8 + (h&7)  within g=(h&127)>>4 group
//   col(cq,w,h) = cq*64 + (w>>3)*2 + (h>>7)
// v2: 256 thr/block, 4 consecutive-h pixels per thread (float4 x loads:
// 1KB/wave/instr vs 256B before, 4x fewer VMEM instructions).
// ---------------------------------------------------------------------------
__global__ __launch_bounds__(256) void qkv_kernel(
    const float* __restrict__ x,
    const float* __restrict__ Wq, const float* __restrict__ bq,
    const float* __restrict__ Wk, const float* __restrict__ bk,
    const float* __restrict__ Wv, const float* __restrict__ bv,
    u16* __restrict__ qt, u16* __restrict__ kt, u16* __restrict__ vm)
{
  __shared__ __align__(16) u16 qs[128 * 64];   // [nl][cq*8+mc]
  __shared__ __align__(16) u16 ks_[128 * 64];
  __shared__ __align__(16) u16 vs[64 * 128];   // [cq*8+mc][nl]

  const int wq = blockIdx.x;   // 0..7
  const int g  = blockIdx.y;   // 0..7
  const int b  = blockIdx.z;   // 0..7
  const int t  = threadIdx.x;  // 0..255
  const int wl = t >> 3;       // 0..31
  const int hg = t & 7;        // 0..7
  const int strip = hg >> 2, hq = hg & 3;
  const int w  = wq * 32 + wl;
  const int h0 = g * 16 + strip * 128 + hq * 4;

  float aq[4][8], ak[4][8], av[4][8];
#pragma unroll
  for (int j = 0; j < 4; j++)
#pragma unroll
    for (int i = 0; i < 8; i++) { aq[j][i] = 0.f; ak[j][i] = 0.f; av[j][i] = 0.f; }

  const float* xp = x + (size_t)b * 64 * 65536 + w * 256 + h0;
#pragma unroll 4
  for (int c = 0; c < 64; c++) {
    const float4 xv = *(const float4*)(xp + (size_t)c * 65536);
    const float xs[4] = {xv.x, xv.y, xv.z, xv.w};
#pragma unroll
    for (int cq = 0; cq < 8; cq++) {
      const float wqv = Wq[cq * 64 + c];
      const float wkv = Wk[cq * 64 + c];
      const float wvv = Wv[cq * 64 + c];
#pragma unroll
      for (int j = 0; j < 4; j++) {
        aq[j][cq] = fmaf(wqv, xs[j], aq[j][cq]);
        ak[j][cq] = fmaf(wkv, xs[j], ak[j][cq]);
        av[j][cq] = fmaf(wvv, xs[j], av[j][cq]);
      }
    }
  }

  const int mc = (wl >> 3) * 2 + strip;      // == ((w>>3)&3)*2 + (h>>7)
#pragma unroll
  for (int j = 0; j < 4; j++) {
    const int h  = h0 + j;
    const int nl = ((h >> 3) & 1) * 64 + (w & 7) * 8 + (h & 7);
#pragma unroll
    for (int cq = 0; cq < 8; cq++) {
      qs[nl * 64 + cq * 8 + mc]    = f32_to_bf16(aq[j][cq] + bq[cq]);
      ks_[nl * 64 + cq * 8 + mc]   = f32_to_bf16(ak[j][cq] + bk[cq]);
      vs[(cq * 8 + mc) * 128 + nl] = f32_to_bf16(av[j][cq] + bv[cq]);
    }
  }
  __syncthreads();

#pragma unroll
  for (int i = 0; i < 4; i++) {
    const int idx = i * 256 + t;           // 0..1023, same coverage as old 1024-thr writeout
    const int nl2 = idx >> 3, cq2 = idx & 7;
    const size_t row = (size_t)b * 1024 + g * 128 + nl2;
    *(uint4*)(qt + row * 512 + cq2 * 64 + wq * 8) = *(const uint4*)(qs + nl2 * 64 + cq2 * 8);
    *(uint4*)(kt + row * 512 + cq2 * 64 + wq * 8) = *(const uint4*)(ks_ + nl2 * 64 + cq2 * 8);
    const int pr = idx >> 4, l16 = idx & 15;
    const int mrow = (pr >> 3) * 64 + wq * 8 + (pr & 7);
    *(uint4*)(vm + ((size_t)b * 512 + mrow) * 1024 + g * 128 + l16 * 8) =
        *(const uint4*)(vs + pr * 128 + l16 * 8);
  }
}

// ---------------------------------------------------------------------------
// NT GEMM: C[M][N] = scale * A[M][K] * B[N][K]^T   (bf16 in, fp32 acc)
// v2: 2-phase double-buffered LDS. Per K-step: issue next tile's
// global_load_lds into buf^1 FIRST, then ds_read+MFMA on buf, then ONE
// __syncthreads (its vmcnt/lgkm drain covers both). Load latency hides
// under MFMA instead of being serialized by two barriers per step.
// blockIdx.x = batch so round-robin XCD dispatch gives each XCD one
// batch's A/B panels (<=4MB, L2-resident).
// XOR-swizzle unchanged: logical chunk c of row r at physical c^(r&7).
// ---------------------------------------------------------------------------
template <int FMW>
__global__ __launch_bounds__(256) void gemm_nt(
    const u16* __restrict__ A, const u16* __restrict__ Bm, u16* __restrict__ Cm,
    int M, int N, int K, float scale)
{
  constexpr int BM = FMW * 32;
  __shared__ __align__(16) u16 As[2][BM * 64];
  __shared__ __align__(16) u16 Bs[2][128 * 64];

  const int bz = blockIdx.x, bn = blockIdx.y, bm = blockIdx.z;
  const int t = threadIdx.x;
  const int lane = t & 63, wid = t >> 6;
  const int wm = wid & 1, wn = wid >> 1;
  const int m0 = bm * BM, n0 = bn * 128;

  const u16* Ab = A + (size_t)bz * M * K + (size_t)m0 * K;
  const u16* Bb = Bm + (size_t)bz * N * K + (size_t)n0 * K;

  floatx4 acc[FMW][4];
#pragma unroll
  for (int i = 0; i < FMW; i++)
#pragma unroll
    for (int j = 0; j < 4; j++) acc[i][j] = (floatx4){0.f, 0.f, 0.f, 0.f};

  const int srow = wid * 8 + (lane >> 3);                   // staging row in 32-row group
  const int scol = (((lane & 7) ^ ((lane >> 3) & 7)) << 3); // swizzled source chunk
  const int l15 = lane & 15, quad = lane >> 4;
  const int cxor = (l15 & 7) << 3;                          // reader chunk XOR (elems)

  // prologue: stage tile 0 into buf 0
#pragma unroll
  for (int i = 0; i < FMW; i++)
    load_lds16(Ab + (size_t)(i * 32 + srow) * K + scol, As[0] + (i * 32 + wid * 8) * 64);
#pragma unroll
  for (int i = 0; i < 4; i++)
    load_lds16(Bb + (size_t)(i * 32 + srow) * K + scol, Bs[0] + (i * 32 + wid * 8) * 64);
  __syncthreads();

  const int nk = K >> 6;
#pragma unroll 2
  for (int kk = 0; kk < nk; kk++) {
    const int cur = kk & 1;
    if (kk + 1 < nk) {                       // issue next-tile stage (no wait)
      const int k1 = (kk + 1) << 6;
#pragma unroll
      for (int i = 0; i < FMW; i++)
        load_lds16(Ab + (size_t)(i * 32 + srow) * K + k1 + scol,
                   As[cur ^ 1] + (i * 32 + wid * 8) * 64);
#pragma unroll
      for (int i = 0; i < 4; i++)
        load_lds16(Bb + (size_t)(i * 32 + srow) * K + k1 + scol,
                   Bs[cur ^ 1] + (i * 32 + wid * 8) * 64);
    }
#pragma unroll
    for (int ks = 0; ks < 2; ks++) {
      const int koff = (ks * 32 + quad * 8) ^ cxor;   // swizzled chunk read
      short8 a[FMW], b[4];
#pragma unroll
      for (int f = 0; f < FMW; f++)
        a[f] = *(const short8*)(As[cur] + (wm * FMW * 16 + f * 16 + l15) * 64 + koff);
#pragma unroll
      for (int f = 0; f < 4; f++)
        b[f] = *(const short8*)(Bs[cur] + (wn * 64 + f * 16 + l15) * 64 + koff);
#pragma unroll
      for (int fm = 0; fm < FMW; fm++)
#pragma unroll
        for (int fn = 0; fn < 4; fn++)
          acc[fm][fn] = __builtin_amdgcn_mfma_f32_16x16x32_bf16(a[fm], b[fn], acc[fm][fn], 0, 0, 0);
    }
    __syncthreads();   // drains this wave's stage loads + ds_reads; buf^1 ready
  }

  // C/D layout (verified): col = lane&15, row = (lane>>4)*4 + reg
  u16* Cb = Cm + (size_t)bz * M * N;
#pragma unroll
  for (int fm = 0; fm < FMW; fm++)
#pragma unroll
    for (int fn = 0; fn < 4; fn++)
#pragma unroll
      for (int r = 0; r < 4; r++) {
        int row = m0 + wm * FMW * 16 + fm * 16 + quad * 4 + r;
        int col = n0 + wn * 64 + fn * 16 + l15;
        Cb[(size_t)row * N + col] = f32_to_bf16(scale * acc[fm][fn][r]);
      }
}

// ---------------------------------------------------------------------------
// Softmax over 1024-wide rows of EP (bf16), in place.
// v2: one WAVE per row (4 rows per 256-thr block). 16 elems/lane, pure
// __shfl_xor reduction — zero __syncthreads, zero LDS.
// ---------------------------------------------------------------------------
__global__ __launch_bounds__(256) void softmax_kernel(u16* __restrict__ EP)
{
  const int r = (blockIdx.x << 2) + (threadIdx.x >> 6);   // 0..8191
  const int lane = threadIdx.x & 63;
  u16* row = EP + (size_t)r * 1024;
  const uint4* rp = (const uint4*)row;

  uint4 v0 = rp[lane * 2];
  uint4 v1 = rp[lane * 2 + 1];
  const u32 wds[8] = {v0.x, v0.y, v0.z, v0.w, v1.x, v1.y, v1.z, v1.w};
  float e[16];
#pragma unroll
  for (int i = 0; i < 8; i++) {
    e[2 * i]     = bf16_to_f32((u16)wds[i]);
    e[2 * i + 1] = bf16_to_f32((u16)(wds[i] >> 16));
  }

  float mx = e[0];
#pragma unroll
  for (int i = 1; i < 16; i++) mx = fmaxf(mx, e[i]);
#pragma unroll
  for (int off = 32; off > 0; off >>= 1) mx = fmaxf(mx, __shfl_xor(mx, off));

  float s = 0.f;
#pragma unroll
  for (int i = 0; i < 16; i++) { e[i] = __expf(e[i] - mx); s += e[i]; }
#pragma unroll
  for (int off = 32; off > 0; off >>= 1) s += __shfl_xor(s, off);

  const float inv = 1.0f / s;
  uint4 o0, o1;
  o0.x = pack2(e[0] * inv,  e[1] * inv);
  o0.y = pack2(e[2] * inv,  e[3] * inv);
  o0.z = pack2(e[4] * inv,  e[5] * inv);
  o0.w = pack2(e[6] * inv,  e[7] * inv);
  o1.x = pack2(e[8] * inv,  e[9] * inv);
  o1.y = pack2(e[10] * inv, e[11] * inv);
  o1.z = pack2(e[12] * inv, e[13] * inv);
  o1.w = pack2(e[14] * inv, e[15] * inv);
  ((uint4*)row)[lane * 2]     = o0;
  ((uint4*)row)[lane * 2 + 1] = o1;
}

// ---------------------------------------------------------------------------
// K5: out = gamma*(Wo . OT + bo) + x
// v2: 4 consecutive pixels per thread — float4 x/out (1KB/wave/instr),
// ushort4 OT reads (8 loads instead of 32 scalar u16).
// ---------------------------------------------------------------------------
__global__ __launch_bounds__(256) void out_kernel(
    const float* __restrict__ x, const u16* __restrict__ OT,
    const float* __restrict__ Wo, const float* __restrict__ bo,
    const float* __restrict__ gammap, float* __restrict__ out)
{
  const int q4 = blockIdx.x * 256 + threadIdx.x;   // 0..131071
  const int b = q4 >> 14;
  const int rem = (q4 & 16383) * 4;                // pixel offset, multiple of 4
  const float gmv = gammap[0];

  const u16* otb = OT + (size_t)b * 524288;
  const int m0 = rem & 511;                        // multiple of 4 -> ushort4 ok
  const int nbase = rem >> 9;                      // constant across the 4 pixels
  float oc[8][4];
#pragma unroll
  for (int cq = 0; cq < 8; cq++) {
    ushort4 hv = *(const ushort4*)(otb + (size_t)(cq * 128 + nbase) * 512 + m0);
    oc[cq][0] = bf16_to_f32(hv.x);
    oc[cq][1] = bf16_to_f32(hv.y);
    oc[cq][2] = bf16_to_f32(hv.z);
    oc[cq][3] = bf16_to_f32(hv.w);
  }

  const float* xb = x + (size_t)b * 4194304 + rem;
  float* ob = out + (size_t)b * 4194304 + rem;
#pragma unroll 4
  for (int o = 0; o < 64; o++) {
    const float4 xv = *(const float4*)(xb + (size_t)o * 65536);
    const float bv = bo[o];
    float a0 = bv, a1 = bv, a2 = bv, a3 = bv;
#pragma unroll
    for (int cq = 0; cq < 8; cq++) {
      const float wv = Wo[o * 8 + cq];
      a0 = fmaf(wv, oc[cq][0], a0);
      a1 = fmaf(wv, oc[cq][1], a1);
      a2 = fmaf(wv, oc[cq][2], a2);
      a3 = fmaf(wv, oc[cq][3], a3);
    }
    float4 rv;
    rv.x = fmaf(gmv, a0, xv.x);
    rv.y = fmaf(gmv, a1, xv.y);
    rv.z = fmaf(gmv, a2, xv.z);
    rv.w = fmaf(gmv, a3, xv.w);
    *(float4*)(ob + (size_t)o * 65536) = rv;
  }
}

// ---------------------------------------------------------------------------
extern "C" void kernel_launch(void* const* d_in, const int* in_sizes, int n_in,
                              void* d_out, int out_size, void* d_ws, size_t ws_size,
                              hipStream_t stream) {
  const float* x  = (const float*)d_in[0];
  const float* Wq = (const float*)d_in[1];
  const float* bq = (const float*)d_in[2];
  const float* Wk = (const float*)d_in[3];
  const float* bk = (const float*)d_in[4];
  const float* Wv = (const float*)d_in[5];
  const float* bv = (const float*)d_in[6];
  const float* Wo = (const float*)d_in[7];
  const float* bo = (const float*)d_in[8];
  const float* gm = (const float*)d_in[9];
  float* out = (float*)d_out;

  // workspace carve: qt | kt | v | EP ; OT reuses qt (dead after gemm1)
  u16* qt = (u16*)d_ws;            // 8*1024*512
  u16* kt = qt + 4194304;
  u16* vm = kt + 4194304;
  u16* EP = vm + 4194304;          // 8*1024*1024
  u16* OT = qt;                    // reuse

  qkv_kernel<<<dim3(8, 8, 8), 256, 0, stream>>>(x, Wq, bq, Wk, bk, Wv, bv, qt, kt, vm);
  // E = qt * kt^T / 32   (M=1024, N=1024, K=512); batch on x for XCD-L2 locality
  gemm_nt<4><<<dim3(8, 8, 8), 256, 0, stream>>>(qt, kt, EP, 1024, 1024, 512, 0.03125f);
  softmax_kernel<<<2048, 256, 0, stream>>>(EP);
  // OT[j][m] = P * v^T   (M=1024, N=512, K=1024)
  gemm_nt<2><<<dim3(8, 4, 16), 256, 0, stream>>>(EP, vm, OT, 1024, 512, 1024, 1.0f);
  out_kernel<<<512, 256, 0, stream>>>(x, OT, Wo, bo, gm, out);
}

// Round 4
// 334.287 us; speedup vs baseline: 1.0373x; 1.0373x over previous
//
#include <hip/hip_runtime.h>
#include <stdint.h>

typedef unsigned short u16;
typedef unsigned int   u32;
typedef __attribute__((ext_vector_type(8))) short  short8;   // 8 x bf16 (4 VGPRs)
typedef __attribute__((ext_vector_type(4))) float  floatx4;  // MFMA acc

__device__ __forceinline__ u16 f32_to_bf16(float f) {
  u32 u = __builtin_bit_cast(u32, f);
  u = (u + 0x7fffu + ((u >> 16) & 1u)) >> 16;
  return (u16)u;
}
__device__ __forceinline__ float bf16_to_f32(u16 h) {
  u32 u = ((u32)h) << 16;
  return __builtin_bit_cast(float, u);
}
__device__ __forceinline__ u32 pack2(float a, float b) {
  return (u32)f32_to_bf16(a) | ((u32)f32_to_bf16(b) << 16);
}

// async global->LDS, 16B per lane. LDS dst = wave-uniform base + lane*16.
__device__ __forceinline__ void load_lds16(const u16* g, u16* l) {
  auto gp = (const __attribute__((address_space(1))) u32*)(uintptr_t)g;
  auto lp = (__attribute__((address_space(3))) u32*)(u32)(uintptr_t)l;
  __builtin_amdgcn_global_load_lds(gp, lp, 16, 0, 0);
}

// ---------------------------------------------------------------------------
// K1: fused QKV 1x1 conv + patch-token layout.
// v3: 512 thr/block (16 waves/CU, was 8 -> occupancy was the bottleneck:
// 17% occ, all pipes <20%). 2 px/thread, float2 x loads.
// qs/ks LDS: [nl][mc*8+cq] stride 72 u16 -> thread writes its 8 cq values
// as ONE ds_write_b128 (was 48 scalar b16 on 4 banks = 16-way conflict,
// 4.1M conflict cycles); reader scalar-gathers across 32 banks (free).
// Token layout (verified): row(w,h)=((h>>3)&1)*64+(w&7)*8+(h&7),
// col(cq,w,h)=cq*64+(w>>3)*2+(h>>7).
// ---------------------------------------------------------------------------
__global__ __launch_bounds__(512) void qkv_kernel(
    const float* __restrict__ x,
    const float* __restrict__ Wq, const float* __restrict__ bq,
    const float* __restrict__ Wk, const float* __restrict__ bk,
    const float* __restrict__ Wv, const float* __restrict__ bv,
    u16* __restrict__ qt, u16* __restrict__ kt, u16* __restrict__ vm)
{
  __shared__ __align__(16) u16 qs[128 * 72];   // [nl][mc*8+cq], stride 72
  __shared__ __align__(16) u16 ks_[128 * 72];
  __shared__ __align__(16) u16 vs[64 * 128];   // [cq*8+mc][nl]

  const int wq = blockIdx.x;   // 0..7
  const int g  = blockIdx.y;   // 0..7
  const int b  = blockIdx.z;   // 0..7
  const int t  = threadIdx.x;  // 0..511
  const int wl = t >> 4;       // 0..31
  const int hg = t & 15;       // 0..15
  const int strip = hg >> 3, hq = hg & 7;
  const int w  = wq * 32 + wl;
  const int h0 = g * 16 + strip * 128 + hq * 2;

  float bqr[8], bkr[8], bvr[8];
#pragma unroll
  for (int i = 0; i < 8; i++) { bqr[i] = bq[i]; bkr[i] = bk[i]; bvr[i] = bv[i]; }

  float aq[2][8], ak[2][8], av[2][8];
#pragma unroll
  for (int j = 0; j < 2; j++)
#pragma unroll
    for (int i = 0; i < 8; i++) { aq[j][i] = 0.f; ak[j][i] = 0.f; av[j][i] = 0.f; }

  const float* xp = x + (size_t)b * 64 * 65536 + w * 256 + h0;
#pragma unroll 4
  for (int c = 0; c < 64; c++) {
    const float2 xv = *(const float2*)(xp + (size_t)c * 65536);
#pragma unroll
    for (int cq = 0; cq < 8; cq++) {
      const float wqv = Wq[cq * 64 + c];
      const float wkv = Wk[cq * 64 + c];
      const float wvv = Wv[cq * 64 + c];
      aq[0][cq] = fmaf(wqv, xv.x, aq[0][cq]);
      aq[1][cq] = fmaf(wqv, xv.y, aq[1][cq]);
      ak[0][cq] = fmaf(wkv, xv.x, ak[0][cq]);
      ak[1][cq] = fmaf(wkv, xv.y, ak[1][cq]);
      av[0][cq] = fmaf(wvv, xv.x, av[0][cq]);
      av[1][cq] = fmaf(wvv, xv.y, av[1][cq]);
    }
  }

  const int mc = ((wl >> 3) & 3) * 2 + strip;  // == ((w>>3)&3)*2 + (h>>7)
#pragma unroll
  for (int j = 0; j < 2; j++) {
    const int h  = h0 + j;
    const int nl = ((h >> 3) & 1) * 64 + (w & 7) * 8 + (h & 7);
    uint4 qv, kv;
    qv.x = pack2(aq[j][0] + bqr[0], aq[j][1] + bqr[1]);
    qv.y = pack2(aq[j][2] + bqr[2], aq[j][3] + bqr[3]);
    qv.z = pack2(aq[j][4] + bqr[4], aq[j][5] + bqr[5]);
    qv.w = pack2(aq[j][6] + bqr[6], aq[j][7] + bqr[7]);
    kv.x = pack2(ak[j][0] + bkr[0], ak[j][1] + bkr[1]);
    kv.y = pack2(ak[j][2] + bkr[2], ak[j][3] + bkr[3]);
    kv.z = pack2(ak[j][4] + bkr[4], ak[j][5] + bkr[5]);
    kv.w = pack2(ak[j][6] + bkr[6], ak[j][7] + bkr[7]);
    *(uint4*)(qs  + nl * 72 + mc * 8) = qv;   // one b128 write, 16B aligned (144*nl+16*mc)
    *(uint4*)(ks_ + nl * 72 + mc * 8) = kv;
#pragma unroll
    for (int cq = 0; cq < 8; cq++)
      vs[(cq * 8 + mc) * 128 + nl] = f32_to_bf16(av[j][cq] + bvr[cq]);
  }
  __syncthreads();

#pragma unroll
  for (int i = 0; i < 2; i++) {
    const int idx = i * 512 + t;           // 0..1023
    const int nl2 = idx >> 3, cq2 = idx & 7;
    const size_t row = (size_t)b * 1024 + g * 128 + nl2;
    const u16* qr = qs  + nl2 * 72 + cq2;  // gather mc=0..7 at stride 8
    const u16* kr = ks_ + nl2 * 72 + cq2;
    uint4 qv, kv;
    qv.x = (u32)qr[0]  | ((u32)qr[8]  << 16);
    qv.y = (u32)qr[16] | ((u32)qr[24] << 16);
    qv.z = (u32)qr[32] | ((u32)qr[40] << 16);
    qv.w = (u32)qr[48] | ((u32)qr[56] << 16);
    kv.x = (u32)kr[0]  | ((u32)kr[8]  << 16);
    kv.y = (u32)kr[16] | ((u32)kr[24] << 16);
    kv.z = (u32)kr[32] | ((u32)kr[40] << 16);
    kv.w = (u32)kr[48] | ((u32)kr[56] << 16);
    *(uint4*)(qt + row * 512 + cq2 * 64 + wq * 8) = qv;
    *(uint4*)(kt + row * 512 + cq2 * 64 + wq * 8) = kv;
    const int pr = idx >> 4, l16 = idx & 15;
    const int mrow = (pr >> 3) * 64 + wq * 8 + (pr & 7);
    *(uint4*)(vm + ((size_t)b * 512 + mrow) * 1024 + g * 128 + l16 * 8) =
        *(const uint4*)(vs + pr * 128 + l16 * 8);
  }
}

// ---------------------------------------------------------------------------
// NT GEMM: C[M][N] = scale * A[M][K] * B[N][K]^T   (bf16 in, fp32 acc)
// v3: 512 threads / 8 waves (2 wm x 4 wn) per block -> 16 waves/CU (was 8;
// latency-bound at 25% occupancy). Wave tile = (BM/2) x 32. Same 2-phase
// dbuf + XOR swizzle (logical chunk c of row r at physical c^(r&7)).
// blockIdx.x = batch -> each XCD owns one batch's panels (L2-resident).
// ---------------------------------------------------------------------------
template <int FMW>
__global__ __launch_bounds__(512) void gemm_nt(
    const u16* __restrict__ A, const u16* __restrict__ Bm, u16* __restrict__ Cm,
    int M, int N, int K, float scale)
{
  constexpr int BM = FMW * 32;
  constexpr int NA = BM / 64;                 // A stage instrs (512 lanes x 16B = 64 rows)
  __shared__ __align__(16) u16 As[2][BM * 64];
  __shared__ __align__(16) u16 Bs[2][128 * 64];

  const int bz = blockIdx.x, bn = blockIdx.y, bm = blockIdx.z;
  const int t = threadIdx.x;
  const int lane = t & 63, wid = t >> 6;      // 8 waves
  const int wm = wid & 1, wn = wid >> 1;      // 2 x 4
  const int m0 = bm * BM, n0 = bn * 128;

  const u16* Ab = A + (size_t)bz * M * K + (size_t)m0 * K;
  const u16* Bb = Bm + (size_t)bz * N * K + (size_t)n0 * K;

  floatx4 acc[FMW][2];
#pragma unroll
  for (int i = 0; i < FMW; i++)
#pragma unroll
    for (int j = 0; j < 2; j++) acc[i][j] = (floatx4){0.f, 0.f, 0.f, 0.f};

  const int srow = wid * 8 + (lane >> 3);                   // 0..63 staging row
  const int scol = (((lane & 7) ^ ((lane >> 3) & 7)) << 3); // swizzled source chunk
  const int l15 = lane & 15, quad = lane >> 4;
  const int cxor = (l15 & 7) << 3;                          // reader chunk XOR (elems)

  // prologue: stage tile 0 into buf 0
#pragma unroll
  for (int i = 0; i < NA; i++)
    load_lds16(Ab + (size_t)(i * 64 + srow) * K + scol, As[0] + (i * 64 + wid * 8) * 64);
#pragma unroll
  for (int i = 0; i < 2; i++)
    load_lds16(Bb + (size_t)(i * 64 + srow) * K + scol, Bs[0] + (i * 64 + wid * 8) * 64);
  __syncthreads();

  const int nk = K >> 6;
#pragma unroll 2
  for (int kk = 0; kk < nk; kk++) {
    const int cur = kk & 1;
    if (kk + 1 < nk) {                       // issue next-tile stage (no wait)
      const int k1 = (kk + 1) << 6;
#pragma unroll
      for (int i = 0; i < NA; i++)
        load_lds16(Ab + (size_t)(i * 64 + srow) * K + k1 + scol,
                   As[cur ^ 1] + (i * 64 + wid * 8) * 64);
#pragma unroll
      for (int i = 0; i < 2; i++)
        load_lds16(Bb + (size_t)(i * 64 + srow) * K + k1 + scol,
                   Bs[cur ^ 1] + (i * 64 + wid * 8) * 64);
    }
#pragma unroll
    for (int ks = 0; ks < 2; ks++) {
      const int koff = (ks * 32 + quad * 8) ^ cxor;   // swizzled chunk read
      short8 a[FMW], b[2];
#pragma unroll
      for (int f = 0; f < FMW; f++)
        a[f] = *(const short8*)(As[cur] + (wm * FMW * 16 + f * 16 + l15) * 64 + koff);
#pragma unroll
      for (int f = 0; f < 2; f++)
        b[f] = *(const short8*)(Bs[cur] + (wn * 32 + f * 16 + l15) * 64 + koff);
#pragma unroll
      for (int fm = 0; fm < FMW; fm++)
#pragma unroll
        for (int fn = 0; fn < 2; fn++)
          acc[fm][fn] = __builtin_amdgcn_mfma_f32_16x16x32_bf16(a[fm], b[fn], acc[fm][fn], 0, 0, 0);
    }
    __syncthreads();
  }

  // C/D layout (verified): col = lane&15, row = (lane>>4)*4 + reg
  u16* Cb = Cm + (size_t)bz * M * N;
#pragma unroll
  for (int fm = 0; fm < FMW; fm++)
#pragma unroll
    for (int fn = 0; fn < 2; fn++)
#pragma unroll
      for (int r = 0; r < 4; r++) {
        int row = m0 + wm * FMW * 16 + fm * 16 + quad * 4 + r;
        int col = n0 + wn * 32 + fn * 16 + l15;
        Cb[(size_t)row * N + col] = f32_to_bf16(scale * acc[fm][fn][r]);
      }
}

// ---------------------------------------------------------------------------
// Softmax over 1024-wide rows of EP (bf16), in place. One wave per row,
// 4 rows per block; pure __shfl_xor reduction, no LDS, no barriers.
// ---------------------------------------------------------------------------
__global__ __launch_bounds__(256) void softmax_kernel(u16* __restrict__ EP)
{
  const int r = (blockIdx.x << 2) + (threadIdx.x >> 6);   // 0..8191
  const int lane = threadIdx.x & 63;
  u16* row = EP + (size_t)r * 1024;
  const uint4* rp = (const uint4*)row;

  uint4 v0 = rp[lane * 2];
  uint4 v1 = rp[lane * 2 + 1];
  const u32 wds[8] = {v0.x, v0.y, v0.z, v0.w, v1.x, v1.y, v1.z, v1.w};
  float e[16];
#pragma unroll
  for (int i = 0; i < 8; i++) {
    e[2 * i]     = bf16_to_f32((u16)wds[i]);
    e[2 * i + 1] = bf16_to_f32((u16)(wds[i] >> 16));
  }

  float mx = e[0];
#pragma unroll
  for (int i = 1; i < 16; i++) mx = fmaxf(mx, e[i]);
#pragma unroll
  for (int off = 32; off > 0; off >>= 1) mx = fmaxf(mx, __shfl_xor(mx, off));

  float s = 0.f;
#pragma unroll
  for (int i = 0; i < 16; i++) { e[i] = __expf(e[i] - mx); s += e[i]; }
#pragma unroll
  for (int off = 32; off > 0; off >>= 1) s += __shfl_xor(s, off);

  const float inv = 1.0f / s;
  uint4 o0, o1;
  o0.x = pack2(e[0] * inv,  e[1] * inv);
  o0.y = pack2(e[2] * inv,  e[3] * inv);
  o0.z = pack2(e[4] * inv,  e[5] * inv);
  o0.w = pack2(e[6] * inv,  e[7] * inv);
  o1.x = pack2(e[8] * inv,  e[9] * inv);
  o1.y = pack2(e[10] * inv, e[11] * inv);
  o1.z = pack2(e[12] * inv, e[13] * inv);
  o1.w = pack2(e[14] * inv, e[15] * inv);
  ((uint4*)row)[lane * 2]     = o0;
  ((uint4*)row)[lane * 2 + 1] = o1;
}

// ---------------------------------------------------------------------------
// K5: out = gamma*(Wo . OT + bo) + x
// v3: 2048 blocks (8/CU, 32 waves/CU): o-loop split in 2 halves across
// blocks (OT re-read +8MB, ~3% traffic) and 2 px/thread (float2).
// ---------------------------------------------------------------------------
__global__ __launch_bounds__(256) void out_kernel(
    const float* __restrict__ x, const u16* __restrict__ OT,
    const float* __restrict__ Wo, const float* __restrict__ bo,
    const float* __restrict__ gammap, float* __restrict__ out)
{
  const int gb = blockIdx.x;                       // 0..2047
  const int osel = gb & 1;
  const int q2 = (gb >> 1) * 256 + threadIdx.x;    // pixel-pair id, 0..262143
  const int b = q2 >> 15;
  const int rem = (q2 & 32767) * 2;                // pixel offset, even
  const float gmv = gammap[0];

  const u16* otb = OT + (size_t)b * 524288;
  const int m0 = rem & 511;
  const int nbase = rem >> 9;
  float oc[8][2];
#pragma unroll
  for (int cq = 0; cq < 8; cq++) {
    ushort2 hv = *(const ushort2*)(otb + (size_t)(cq * 128 + nbase) * 512 + m0);
    oc[cq][0] = bf16_to_f32(hv.x);
    oc[cq][1] = bf16_to_f32(hv.y);
  }

  const size_t obase = (size_t)b * 4194304 + rem + (size_t)osel * 32 * 65536;
  const float* xb = x + obase;
  float* ob = out + obase;
  const int o0 = osel * 32;
#pragma unroll 4
  for (int oo = 0; oo < 32; oo++) {
    const int o = o0 + oo;
    const float2 xv = *(const float2*)(xb + (size_t)oo * 65536);
    const float bv = bo[o];
    float a0 = bv, a1 = bv;
#pragma unroll
    for (int cq = 0; cq < 8; cq++) {
      const float wv = Wo[o * 8 + cq];
      a0 = fmaf(wv, oc[cq][0], a0);
      a1 = fmaf(wv, oc[cq][1], a1);
    }
    float2 rv;
    rv.x = fmaf(gmv, a0, xv.x);
    rv.y = fmaf(gmv, a1, xv.y);
    *(float2*)(ob + (size_t)oo * 65536) = rv;
  }
}

// ---------------------------------------------------------------------------
extern "C" void kernel_launch(void* const* d_in, const int* in_sizes, int n_in,
                              void* d_out, int out_size, void* d_ws, size_t ws_size,
                              hipStream_t stream) {
  const float* x  = (const float*)d_in[0];
  const float* Wq = (const float*)d_in[1];
  const float* bq = (const float*)d_in[2];
  const float* Wk = (const float*)d_in[3];
  const float* bk = (const float*)d_in[4];
  const float* Wv = (const float*)d_in[5];
  const float* bv = (const float*)d_in[6];
  const float* Wo = (const float*)d_in[7];
  const float* bo = (const float*)d_in[8];
  const float* gm = (const float*)d_in[9];
  float* out = (float*)d_out;

  // workspace carve: qt | kt | v | EP ; OT reuses qt (dead after gemm1)
  u16* qt = (u16*)d_ws;            // 8*1024*512
  u16* kt = qt + 4194304;
  u16* vm = kt + 4194304;
  u16* EP = vm + 4194304;          // 8*1024*1024
  u16* OT = qt;                    // reuse

  qkv_kernel<<<dim3(8, 8, 8), 512, 0, stream>>>(x, Wq, bq, Wk, bk, Wv, bv, qt, kt, vm);
  // E = qt * kt^T / 32   (M=1024, N=1024, K=512); batch on x for XCD-L2 locality
  gemm_nt<4><<<dim3(8, 8, 8), 512, 0, stream>>>(qt, kt, EP, 1024, 1024, 512, 0.03125f);
  softmax_kernel<<<2048, 256, 0, stream>>>(EP);
  // OT[j][m] = P * v^T   (M=1024, N=512, K=1024)
  gemm_nt<2><<<dim3(8, 4, 16), 512, 0, stream>>>(EP, vm, OT, 1024, 512, 1024, 1.0f);
  out_kernel<<<2048, 256, 0, stream>>>(x, OT, Wo, bo, gm, out);
}

// Round 5
// 323.936 us; speedup vs baseline: 1.0704x; 1.0320x over previous
//
#include <hip/hip_runtime.h>
#include <stdint.h>

typedef unsigned short u16;
typedef unsigned int   u32;
typedef __attribute__((ext_vector_type(8))) short  short8;   // 8 x bf16 (4 VGPRs)
typedef __attribute__((ext_vector_type(4))) float  floatx4;  // MFMA acc

__device__ __forceinline__ u16 f32_to_bf16(float f) {
  u32 u = __builtin_bit_cast(u32, f);
  u = (u + 0x7fffu + ((u >> 16) & 1u)) >> 16;
  return (u16)u;
}
__device__ __forceinline__ float bf16_to_f32(u16 h) {
  u32 u = ((u32)h) << 16;
  return __builtin_bit_cast(float, u);
}
__device__ __forceinline__ u32 pack2(float a, float b) {
  return (u32)f32_to_bf16(a) | ((u32)f32_to_bf16(b) << 16);
}

// async global->LDS, 16B per lane. LDS dst = wave-uniform base + lane*16.
__device__ __forceinline__ void load_lds16(const u16* g, u16* l) {
  auto gp = (const __attribute__((address_space(1))) u32*)(uintptr_t)g;
  auto lp = (__attribute__((address_space(3))) u32*)(u32)(uintptr_t)l;
  __builtin_amdgcn_global_load_lds(gp, lp, 16, 0, 0);
}

// ---------------------------------------------------------------------------
// K1: fused QKV 1x1 conv + patch-token layout.
// v4: ONE change vs v3 — qt/kt K-dim permutation. Old col = cq*64+wq*8+mc:
// each 64-B sector of a row got 16-B pieces from FOUR blocks (wq=0..3) on
// four different XCDs -> four non-coherent L2s with partial-dirty copies of
// the same sector -> partial-line RMW evictions. This write pattern was the
// only thing invariant across v1/v2/v3, all stuck at 80.5us / 1.35 TB/s.
// New col = wq*64+cq*8+mc: block wq owns contiguous cols [wq*64,wq*64+64)
// (2 full sectors/row), stores are 8 lanes x 16 B = 128 B contiguous.
// gemm1 consumes qt,kt symmetrically over K -> identical results (K-order
// is arbitrary when applied to BOTH operands). No other consumer of qt/kt.
// Token layout otherwise unchanged (verified):
//   row(w,h)=((h>>3)&1)*64+(w&7)*8+(h&7), g=(h&127)>>4.
// ---------------------------------------------------------------------------
__global__ __launch_bounds__(512) void qkv_kernel(
    const float* __restrict__ x,
    const float* __restrict__ Wq, const float* __restrict__ bq,
    const float* __restrict__ Wk, const float* __restrict__ bk,
    const float* __restrict__ Wv, const float* __restrict__ bv,
    u16* __restrict__ qt, u16* __restrict__ kt, u16* __restrict__ vm)
{
  __shared__ __align__(16) u16 qs[128 * 72];   // [nl][mc*8+cq], stride 72
  __shared__ __align__(16) u16 ks_[128 * 72];
  __shared__ __align__(16) u16 vs[64 * 128];   // [cq*8+mc][nl]

  const int wq = blockIdx.x;   // 0..7
  const int g  = blockIdx.y;   // 0..7
  const int b  = blockIdx.z;   // 0..7
  const int t  = threadIdx.x;  // 0..511
  const int wl = t >> 4;       // 0..31
  const int hg = t & 15;       // 0..15
  const int strip = hg >> 3, hq = hg & 7;
  const int w  = wq * 32 + wl;
  const int h0 = g * 16 + strip * 128 + hq * 2;

  float bqr[8], bkr[8], bvr[8];
#pragma unroll
  for (int i = 0; i < 8; i++) { bqr[i] = bq[i]; bkr[i] = bk[i]; bvr[i] = bv[i]; }

  float aq[2][8], ak[2][8], av[2][8];
#pragma unroll
  for (int j = 0; j < 2; j++)
#pragma unroll
    for (int i = 0; i < 8; i++) { aq[j][i] = 0.f; ak[j][i] = 0.f; av[j][i] = 0.f; }

  const float* xp = x + (size_t)b * 64 * 65536 + w * 256 + h0;
#pragma unroll 4
  for (int c = 0; c < 64; c++) {
    const float2 xv = *(const float2*)(xp + (size_t)c * 65536);
#pragma unroll
    for (int cq = 0; cq < 8; cq++) {
      const float wqv = Wq[cq * 64 + c];
      const float wkv = Wk[cq * 64 + c];
      const float wvv = Wv[cq * 64 + c];
      aq[0][cq] = fmaf(wqv, xv.x, aq[0][cq]);
      aq[1][cq] = fmaf(wqv, xv.y, aq[1][cq]);
      ak[0][cq] = fmaf(wkv, xv.x, ak[0][cq]);
      ak[1][cq] = fmaf(wkv, xv.y, ak[1][cq]);
      av[0][cq] = fmaf(wvv, xv.x, av[0][cq]);
      av[1][cq] = fmaf(wvv, xv.y, av[1][cq]);
    }
  }

  const int mc = ((wl >> 3) & 3) * 2 + strip;  // == ((w>>3)&3)*2 + (h>>7)
#pragma unroll
  for (int j = 0; j < 2; j++) {
    const int h  = h0 + j;
    const int nl = ((h >> 3) & 1) * 64 + (w & 7) * 8 + (h & 7);
    uint4 qv, kv;
    qv.x = pack2(aq[j][0] + bqr[0], aq[j][1] + bqr[1]);
    qv.y = pack2(aq[j][2] + bqr[2], aq[j][3] + bqr[3]);
    qv.z = pack2(aq[j][4] + bqr[4], aq[j][5] + bqr[5]);
    qv.w = pack2(aq[j][6] + bqr[6], aq[j][7] + bqr[7]);
    kv.x = pack2(ak[j][0] + bkr[0], ak[j][1] + bkr[1]);
    kv.y = pack2(ak[j][2] + bkr[2], ak[j][3] + bkr[3]);
    kv.z = pack2(ak[j][4] + bkr[4], ak[j][5] + bkr[5]);
    kv.w = pack2(ak[j][6] + bkr[6], ak[j][7] + bkr[7]);
    *(uint4*)(qs  + nl * 72 + mc * 8) = qv;   // one b128 write, 16B aligned (144*nl+16*mc)
    *(uint4*)(ks_ + nl * 72 + mc * 8) = kv;
#pragma unroll
    for (int cq = 0; cq < 8; cq++)
      vs[(cq * 8 + mc) * 128 + nl] = f32_to_bf16(av[j][cq] + bvr[cq]);
  }
  __syncthreads();

#pragma unroll
  for (int i = 0; i < 2; i++) {
    const int idx = i * 512 + t;           // 0..1023
    const int nl2 = idx >> 3, cq2 = idx & 7;
    const size_t row = (size_t)b * 1024 + g * 128 + nl2;
    const u16* qr = qs  + nl2 * 72 + cq2;  // gather mc=0..7 at stride 8
    const u16* kr = ks_ + nl2 * 72 + cq2;
    uint4 qv, kv;
    qv.x = (u32)qr[0]  | ((u32)qr[8]  << 16);
    qv.y = (u32)qr[16] | ((u32)qr[24] << 16);
    qv.z = (u32)qr[32] | ((u32)qr[40] << 16);
    qv.w = (u32)qr[48] | ((u32)qr[56] << 16);
    kv.x = (u32)kr[0]  | ((u32)kr[8]  << 16);
    kv.y = (u32)kr[16] | ((u32)kr[24] << 16);
    kv.z = (u32)kr[32] | ((u32)kr[40] << 16);
    kv.w = (u32)kr[48] | ((u32)kr[56] << 16);
    // v4: K-permuted layout k = wq*64 + cq*8 + mc (was cq*64 + wq*8 + mc).
    // 8 consecutive lanes (cq2=0..7) write 128 B contiguous; block wq owns
    // its sectors exclusively (single XCD, full-line evictions).
    *(uint4*)(qt + row * 512 + wq * 64 + cq2 * 8) = qv;
    *(uint4*)(kt + row * 512 + wq * 64 + cq2 * 8) = kv;
    const int pr = idx >> 4, l16 = idx & 15;
    const int mrow = (pr >> 3) * 64 + wq * 8 + (pr & 7);
    *(uint4*)(vm + ((size_t)b * 512 + mrow) * 1024 + g * 128 + l16 * 8) =
        *(const uint4*)(vs + pr * 128 + l16 * 8);
  }
}

// ---------------------------------------------------------------------------
// NT GEMM: C[M][N] = scale * A[M][K] * B[N][K]^T   (bf16 in, fp32 acc)
// v3: 512 threads / 8 waves (2 wm x 4 wn) per block -> 16 waves/CU. Wave
// tile = (BM/2) x 32. 2-phase dbuf + XOR swizzle (logical chunk c of row r
// at physical c^(r&7)). blockIdx.x = batch -> XCD-L2 locality.
// ---------------------------------------------------------------------------
template <int FMW>
__global__ __launch_bounds__(512) void gemm_nt(
    const u16* __restrict__ A, const u16* __restrict__ Bm, u16* __restrict__ Cm,
    int M, int N, int K, float scale)
{
  constexpr int BM = FMW * 32;
  constexpr int NA = BM / 64;                 // A stage instrs (512 lanes x 16B = 64 rows)
  __shared__ __align__(16) u16 As[2][BM * 64];
  __shared__ __align__(16) u16 Bs[2][128 * 64];

  const int bz = blockIdx.x, bn = blockIdx.y, bm = blockIdx.z;
  const int t = threadIdx.x;
  const int lane = t & 63, wid = t >> 6;      // 8 waves
  const int wm = wid & 1, wn = wid >> 1;      // 2 x 4
  const int m0 = bm * BM, n0 = bn * 128;

  const u16* Ab = A + (size_t)bz * M * K + (size_t)m0 * K;
  const u16* Bb = Bm + (size_t)bz * N * K + (size_t)n0 * K;

  floatx4 acc[FMW][2];
#pragma unroll
  for (int i = 0; i < FMW; i++)
#pragma unroll
    for (int j = 0; j < 2; j++) acc[i][j] = (floatx4){0.f, 0.f, 0.f, 0.f};

  const int srow = wid * 8 + (lane >> 3);                   // 0..63 staging row
  const int scol = (((lane & 7) ^ ((lane >> 3) & 7)) << 3); // swizzled source chunk
  const int l15 = lane & 15, quad = lane >> 4;
  const int cxor = (l15 & 7) << 3;                          // reader chunk XOR (elems)

  // prologue: stage tile 0 into buf 0
#pragma unroll
  for (int i = 0; i < NA; i++)
    load_lds16(Ab + (size_t)(i * 64 + srow) * K + scol, As[0] + (i * 64 + wid * 8) * 64);
#pragma unroll
  for (int i = 0; i < 2; i++)
    load_lds16(Bb + (size_t)(i * 64 + srow) * K + scol, Bs[0] + (i * 64 + wid * 8) * 64);
  __syncthreads();

  const int nk = K >> 6;
#pragma unroll 2
  for (int kk = 0; kk < nk; kk++) {
    const int cur = kk & 1;
    if (kk + 1 < nk) {                       // issue next-tile stage (no wait)
      const int k1 = (kk + 1) << 6;
#pragma unroll
      for (int i = 0; i < NA; i++)
        load_lds16(Ab + (size_t)(i * 64 + srow) * K + k1 + scol,
                   As[cur ^ 1] + (i * 64 + wid * 8) * 64);
#pragma unroll
      for (int i = 0; i < 2; i++)
        load_lds16(Bb + (size_t)(i * 64 + srow) * K + k1 + scol,
                   Bs[cur ^ 1] + (i * 64 + wid * 8) * 64);
    }
#pragma unroll
    for (int ks = 0; ks < 2; ks++) {
      const int koff = (ks * 32 + quad * 8) ^ cxor;   // swizzled chunk read
      short8 a[FMW], b[2];
#pragma unroll
      for (int f = 0; f < FMW; f++)
        a[f] = *(const short8*)(As[cur] + (wm * FMW * 16 + f * 16 + l15) * 64 + koff);
#pragma unroll
      for (int f = 0; f < 2; f++)
        b[f] = *(const short8*)(Bs[cur] + (wn * 32 + f * 16 + l15) * 64 + koff);
#pragma unroll
      for (int fm = 0; fm < FMW; fm++)
#pragma unroll
        for (int fn = 0; fn < 2; fn++)
          acc[fm][fn] = __builtin_amdgcn_mfma_f32_16x16x32_bf16(a[fm], b[fn], acc[fm][fn], 0, 0, 0);
    }
    __syncthreads();
  }

  // C/D layout (verified): col = lane&15, row = (lane>>4)*4 + reg
  u16* Cb = Cm + (size_t)bz * M * N;
#pragma unroll
  for (int fm = 0; fm < FMW; fm++)
#pragma unroll
    for (int fn = 0; fn < 2; fn++)
#pragma unroll
      for (int r = 0; r < 4; r++) {
        int row = m0 + wm * FMW * 16 + fm * 16 + quad * 4 + r;
        int col = n0 + wn * 32 + fn * 16 + l15;
        Cb[(size_t)row * N + col] = f32_to_bf16(scale * acc[fm][fn][r]);
      }
}

// ---------------------------------------------------------------------------
// Softmax over 1024-wide rows of EP (bf16), in place. One wave per row,
// 4 rows per block; pure __shfl_xor reduction, no LDS, no barriers.
// ---------------------------------------------------------------------------
__global__ __launch_bounds__(256) void softmax_kernel(u16* __restrict__ EP)
{
  const int r = (blockIdx.x << 2) + (threadIdx.x >> 6);   // 0..8191
  const int lane = threadIdx.x & 63;
  u16* row = EP + (size_t)r * 1024;
  const uint4* rp = (const uint4*)row;

  uint4 v0 = rp[lane * 2];
  uint4 v1 = rp[lane * 2 + 1];
  const u32 wds[8] = {v0.x, v0.y, v0.z, v0.w, v1.x, v1.y, v1.z, v1.w};
  float e[16];
#pragma unroll
  for (int i = 0; i < 8; i++) {
    e[2 * i]     = bf16_to_f32((u16)wds[i]);
    e[2 * i + 1] = bf16_to_f32((u16)(wds[i] >> 16));
  }

  float mx = e[0];
#pragma unroll
  for (int i = 1; i < 16; i++) mx = fmaxf(mx, e[i]);
#pragma unroll
  for (int off = 32; off > 0; off >>= 1) mx = fmaxf(mx, __shfl_xor(mx, off));

  float s = 0.f;
#pragma unroll
  for (int i = 0; i < 16; i++) { e[i] = __expf(e[i] - mx); s += e[i]; }
#pragma unroll
  for (int off = 32; off > 0; off >>= 1) s += __shfl_xor(s, off);

  const float inv = 1.0f / s;
  uint4 o0, o1;
  o0.x = pack2(e[0] * inv,  e[1] * inv);
  o0.y = pack2(e[2] * inv,  e[3] * inv);
  o0.z = pack2(e[4] * inv,  e[5] * inv);
  o0.w = pack2(e[6] * inv,  e[7] * inv);
  o1.x = pack2(e[8] * inv,  e[9] * inv);
  o1.y = pack2(e[10] * inv, e[11] * inv);
  o1.z = pack2(e[12] * inv, e[13] * inv);
  o1.w = pack2(e[14] * inv, e[15] * inv);
  ((uint4*)row)[lane * 2]     = o0;
  ((uint4*)row)[lane * 2 + 1] = o1;
}

// ---------------------------------------------------------------------------
// K5: out = gamma*(Wo . OT + bo) + x
// v3: 2048 blocks (8/CU, 32 waves/CU): o-loop split in 2 halves across
// blocks (OT re-read +8MB, ~3% traffic) and 2 px/thread (float2).
// ---------------------------------------------------------------------------
__global__ __launch_bounds__(256) void out_kernel(
    const float* __restrict__ x, const u16* __restrict__ OT,
    const float* __restrict__ Wo, const float* __restrict__ bo,
    const float* __restrict__ gammap, float* __restrict__ out)
{
  const int gb = blockIdx.x;                       // 0..2047
  const int osel = gb & 1;
  const int q2 = (gb >> 1) * 256 + threadIdx.x;    // pixel-pair id, 0..262143
  const int b = q2 >> 15;
  const int rem = (q2 & 32767) * 2;                // pixel offset, even
  const float gmv = gammap[0];

  const u16* otb = OT + (size_t)b * 524288;
  const int m0 = rem & 511;
  const int nbase = rem >> 9;
  float oc[8][2];
#pragma unroll
  for (int cq = 0; cq < 8; cq++) {
    ushort2 hv = *(const ushort2*)(otb + (size_t)(cq * 128 + nbase) * 512 + m0);
    oc[cq][0] = bf16_to_f32(hv.x);
    oc[cq][1] = bf16_to_f32(hv.y);
  }

  const size_t obase = (size_t)b * 4194304 + rem + (size_t)osel * 32 * 65536;
  const float* xb = x + obase;
  float* ob = out + obase;
  const int o0 = osel * 32;
#pragma unroll 4
  for (int oo = 0; oo < 32; oo++) {
    const int o = o0 + oo;
    const float2 xv = *(const float2*)(xb + (size_t)oo * 65536);
    const float bv = bo[o];
    float a0 = bv, a1 = bv;
#pragma unroll
    for (int cq = 0; cq < 8; cq++) {
      const float wv = Wo[o * 8 + cq];
      a0 = fmaf(wv, oc[cq][0], a0);
      a1 = fmaf(wv, oc[cq][1], a1);
    }
    float2 rv;
    rv.x = fmaf(gmv, a0, xv.x);
    rv.y = fmaf(gmv, a1, xv.y);
    *(float2*)(ob + (size_t)oo * 65536) = rv;
  }
}

// ---------------------------------------------------------------------------
extern "C" void kernel_launch(void* const* d_in, const int* in_sizes, int n_in,
                              void* d_out, int out_size, void* d_ws, size_t ws_size,
                              hipStream_t stream) {
  const float* x  = (const float*)d_in[0];
  const float* Wq = (const float*)d_in[1];
  const float* bq = (const float*)d_in[2];
  const float* Wk = (const float*)d_in[3];
  const float* bk = (const float*)d_in[4];
  const float* Wv = (const float*)d_in[5];
  const float* bv = (const float*)d_in[6];
  const float* Wo = (const float*)d_in[7];
  const float* bo = (const float*)d_in[8];
  const float* gm = (const float*)d_in[9];
  float* out = (float*)d_out;

  // workspace carve: qt | kt | v | EP ; OT reuses qt (dead after gemm1)
  u16* qt = (u16*)d_ws;            // 8*1024*512
  u16* kt = qt + 4194304;
  u16* vm = kt + 4194304;
  u16* EP = vm + 4194304;          // 8*1024*1024
  u16* OT = qt;                    // reuse

  qkv_kernel<<<dim3(8, 8, 8), 512, 0, stream>>>(x, Wq, bq, Wk, bk, Wv, bv, qt, kt, vm);
  // E = qt * kt^T / 32   (M=1024, N=1024, K=512); batch on x for XCD-L2 locality
  gemm_nt<4><<<dim3(8, 8, 8), 512, 0, stream>>>(qt, kt, EP, 1024, 1024, 512, 0.03125f);
  softmax_kernel<<<2048, 256, 0, stream>>>(EP);
  // OT[j][m] = P * v^T   (M=1024, N=512, K=1024)
  gemm_nt<2><<<dim3(8, 4, 16), 512, 0, stream>>>(EP, vm, OT, 1024, 512, 1024, 1.0f);
  out_kernel<<<2048, 256, 0, stream>>>(x, OT, Wo, bo, gm, out);
}

// Round 6
// 323.370 us; speedup vs baseline: 1.0723x; 1.0017x over previous
//
#include <hip/hip_runtime.h>
#include <stdint.h>

typedef unsigned short u16;
typedef unsigned int   u32;
typedef __attribute__((ext_vector_type(8))) short  short8;   // 8 x bf16 (4 VGPRs)
typedef __attribute__((ext_vector_type(4))) float  floatx4;  // MFMA acc

__device__ __forceinline__ u16 f32_to_bf16(float f) {
  u32 u = __builtin_bit_cast(u32, f);
  u = (u + 0x7fffu + ((u >> 16) & 1u)) >> 16;
  return (u16)u;
}
__device__ __forceinline__ float bf16_to_f32(u16 h) {
  u32 u = ((u32)h) << 16;
  return __builtin_bit_cast(float, u);
}
__device__ __forceinline__ u32 pack2(float a, float b) {
  return (u32)f32_to_bf16(a) | ((u32)f32_to_bf16(b) << 16);
}

// async global->LDS, 16B per lane. LDS dst = wave-uniform base + lane*16.
__device__ __forceinline__ void load_lds16(const u16* g, u16* l) {
  auto gp = (const __attribute__((address_space(1))) u32*)(uintptr_t)g;
  auto lp = (__attribute__((address_space(3))) u32*)(u32)(uintptr_t)l;
  __builtin_amdgcn_global_load_lds(gp, lp, 16, 0, 0);
}

// LDS token-index swizzle: tk's low bits are wave-uniform (wrow) -> fold the
// lane-varying high bits (tk 6..8) into bank bits (tk 3..5). Bijective on
// [0,1024), preserves bit0 (consecutive even/odd token pairs stay adjacent).
__device__ __forceinline__ int swz(int tk) { return tk ^ ((tk >> 3) & 56); }

// ---------------------------------------------------------------------------
// K1: fused QKV 1x1 conv + patch-token layout.
// v5: read-coalescing rebuild. Old blocks covered 16-px h-strips -> every
// wave x-load was 8 scattered 64-B segments; latency-bound at ~1.35 TB/s
// across v1-v4 (occupancy 2x'd with no effect -> MLP-bound, not occ-bound).
// New block = 8 w-rows x 128 contiguous h (one strip): wave = one w-row,
// lane reads float2 at h=2*lane -> 512 B contiguous per instruction.
// Token math (verified): n = ((h>>3)&15)*64 + (w&7)*8 + (h&7),
// m_true = cq*64 + (w>>3)*2 + (h>>7) = cq*64 + wq*8 + mc,
// with wq = w>>5 = wg>>2 and mc = ((w>>3)&3)*2 + (h>>7) = (wg&3)*2 + s.
// (wg,s) <-> (wq,mc) is a bijection: 64 blocks/batch cover all 512 K-cols.
// qt/kt K-dim RE-permuted (applied to BOTH gemm1 operands -> results
// invariant): k = wq*64 + mc*8 + cq. Block writes one contiguous 16-B
// chunk per qt/kt row; vm rows written as full 2-KB contiguous rows.
// ---------------------------------------------------------------------------
__global__ __launch_bounds__(512) void qkv_kernel(
    const float* __restrict__ x,
    const float* __restrict__ Wq, const float* __restrict__ bq,
    const float* __restrict__ Wk, const float* __restrict__ bk,
    const float* __restrict__ Wv, const float* __restrict__ bv,
    u16* __restrict__ qt, u16* __restrict__ kt, u16* __restrict__ vm)
{
  __shared__ __align__(16) u16 qs[8 * 1024];   // [cq][swz(token)]
  __shared__ __align__(16) u16 ks_[8 * 1024];
  __shared__ __align__(16) u16 vs[8 * 1024];

  const int wg = blockIdx.x;   // 0..31 (w-group of 8)
  const int s  = blockIdx.y;   // 0..1  (h strip)
  const int b  = blockIdx.z;   // 0..7
  const int t  = threadIdx.x;  // 0..511
  const int wrow = t >> 6;     // 0..7 (wave id = w-row)
  const int hl2  = (t & 63) * 2;          // 0..126, even
  const int w  = wg * 8 + wrow;
  const int h  = s * 128 + hl2;

  float bqr[8], bkr[8], bvr[8];
#pragma unroll
  for (int i = 0; i < 8; i++) { bqr[i] = bq[i]; bkr[i] = bk[i]; bvr[i] = bv[i]; }

  float aq[2][8], ak[2][8], av[2][8];
#pragma unroll
  for (int j = 0; j < 2; j++)
#pragma unroll
    for (int i = 0; i < 8; i++) { aq[j][i] = 0.f; ak[j][i] = 0.f; av[j][i] = 0.f; }

  const float* xp = x + (size_t)b * 64 * 65536 + w * 256 + h;
#pragma unroll 4
  for (int c = 0; c < 64; c++) {
    const float2 xv = *(const float2*)(xp + (size_t)c * 65536);   // 512 B/wave-instr
#pragma unroll
    for (int cq = 0; cq < 8; cq++) {
      const float wqv = Wq[cq * 64 + c];
      const float wkv = Wk[cq * 64 + c];
      const float wvv = Wv[cq * 64 + c];
      aq[0][cq] = fmaf(wqv, xv.x, aq[0][cq]);
      aq[1][cq] = fmaf(wqv, xv.y, aq[1][cq]);
      ak[0][cq] = fmaf(wkv, xv.x, ak[0][cq]);
      ak[1][cq] = fmaf(wkv, xv.y, ak[1][cq]);
      av[0][cq] = fmaf(wvv, xv.x, av[0][cq]);
      av[1][cq] = fmaf(wvv, xv.y, av[1][cq]);
    }
  }

  // thread's two tokens are consecutive: tk0 (even) and tk0+1
  const int tk0 = ((hl2 >> 3) << 6) | (wrow << 3) | (hl2 & 7);
  const int st  = swz(tk0);    // swz preserves +1 adjacency (bit0 untouched)
#pragma unroll
  for (int cq = 0; cq < 8; cq++) {
    *(u32*)(qs  + cq * 1024 + st) = pack2(aq[0][cq] + bqr[cq], aq[1][cq] + bqr[cq]);
    *(u32*)(ks_ + cq * 1024 + st) = pack2(ak[0][cq] + bkr[cq], ak[1][cq] + bkr[cq]);
    *(u32*)(vs  + cq * 1024 + st) = pack2(av[0][cq] + bvr[cq], av[1][cq] + bvr[cq]);
  }
  __syncthreads();

  const int wq = wg >> 2;
  const int mc = (wg & 3) * 2 + s;
  const int colbase = wq * 64 + mc * 8;    // v5 K-perm: k = wq*64 + mc*8 + cq

  // qt/kt: per token row, one contiguous 16-B (8 cq) chunk. 2 tokens/thread.
#pragma unroll
  for (int i = 0; i < 2; i++) {
    const int tk = i * 512 + t;
    const int sk = swz(tk);
    uint4 qv, kv;
    qv.x = (u32)qs[sk]        | ((u32)qs[1024 + sk] << 16);
    qv.y = (u32)qs[2048 + sk] | ((u32)qs[3072 + sk] << 16);
    qv.z = (u32)qs[4096 + sk] | ((u32)qs[5120 + sk] << 16);
    qv.w = (u32)qs[6144 + sk] | ((u32)qs[7168 + sk] << 16);
    kv.x = (u32)ks_[sk]        | ((u32)ks_[1024 + sk] << 16);
    kv.y = (u32)ks_[2048 + sk] | ((u32)ks_[3072 + sk] << 16);
    kv.z = (u32)ks_[4096 + sk] | ((u32)ks_[5120 + sk] << 16);
    kv.w = (u32)ks_[6144 + sk] | ((u32)ks_[7168 + sk] << 16);
    *(uint4*)(qt + ((size_t)b * 1024 + tk) * 512 + colbase) = qv;
    *(uint4*)(kt + ((size_t)b * 1024 + tk) * 512 + colbase) = kv;
  }

  // vm: 8 full rows (m = cq*64 + wq*8 + mc), each 1024 tokens contiguous.
#pragma unroll
  for (int cq = 0; cq < 8; cq++) {
    const int mrow = cq * 64 + wq * 8 + mc;
    const u32 val = *(const u32*)(vs + cq * 1024 + swz(2 * t));   // tokens 2t,2t+1
    *(u32*)(vm + ((size_t)b * 512 + mrow) * 1024 + 2 * t) = val;
  }
}

// ---------------------------------------------------------------------------
// NT GEMM: C[M][N] = scale * A[M][K] * B[N][K]^T   (bf16 in, fp32 acc)
// v3: 512 threads / 8 waves (2 wm x 4 wn) per block -> 16 waves/CU. Wave
// tile = (BM/2) x 32. 2-phase dbuf + XOR swizzle (logical chunk c of row r
// at physical c^(r&7)). blockIdx.x = batch -> XCD-L2 locality.
// ---------------------------------------------------------------------------
template <int FMW>
__global__ __launch_bounds__(512) void gemm_nt(
    const u16* __restrict__ A, const u16* __restrict__ Bm, u16* __restrict__ Cm,
    int M, int N, int K, float scale)
{
  constexpr int BM = FMW * 32;
  constexpr int NA = BM / 64;                 // A stage instrs (512 lanes x 16B = 64 rows)
  __shared__ __align__(16) u16 As[2][BM * 64];
  __shared__ __align__(16) u16 Bs[2][128 * 64];

  const int bz = blockIdx.x, bn = blockIdx.y, bm = blockIdx.z;
  const int t = threadIdx.x;
  const int lane = t & 63, wid = t >> 6;      // 8 waves
  const int wm = wid & 1, wn = wid >> 1;      // 2 x 4
  const int m0 = bm * BM, n0 = bn * 128;

  const u16* Ab = A + (size_t)bz * M * K + (size_t)m0 * K;
  const u16* Bb = Bm + (size_t)bz * N * K + (size_t)n0 * K;

  floatx4 acc[FMW][2];
#pragma unroll
  for (int i = 0; i < FMW; i++)
#pragma unroll
    for (int j = 0; j < 2; j++) acc[i][j] = (floatx4){0.f, 0.f, 0.f, 0.f};

  const int srow = wid * 8 + (lane >> 3);                   // 0..63 staging row
  const int scol = (((lane & 7) ^ ((lane >> 3) & 7)) << 3); // swizzled source chunk
  const int l15 = lane & 15, quad = lane >> 4;
  const int cxor = (l15 & 7) << 3;                          // reader chunk XOR (elems)

  // prologue: stage tile 0 into buf 0
#pragma unroll
  for (int i = 0; i < NA; i++)
    load_lds16(Ab + (size_t)(i * 64 + srow) * K + scol, As[0] + (i * 64 + wid * 8) * 64);
#pragma unroll
  for (int i = 0; i < 2; i++)
    load_lds16(Bb + (size_t)(i * 64 + srow) * K + scol, Bs[0] + (i * 64 + wid * 8) * 64);
  __syncthreads();

  const int nk = K >> 6;
#pragma unroll 2
  for (int kk = 0; kk < nk; kk++) {
    const int cur = kk & 1;
    if (kk + 1 < nk) {                       // issue next-tile stage (no wait)
      const int k1 = (kk + 1) << 6;
#pragma unroll
      for (int i = 0; i < NA; i++)
        load_lds16(Ab + (size_t)(i * 64 + srow) * K + k1 + scol,
                   As[cur ^ 1] + (i * 64 + wid * 8) * 64);
#pragma unroll
      for (int i = 0; i < 2; i++)
        load_lds16(Bb + (size_t)(i * 64 + srow) * K + k1 + scol,
                   Bs[cur ^ 1] + (i * 64 + wid * 8) * 64);
    }
#pragma unroll
    for (int ks = 0; ks < 2; ks++) {
      const int koff = (ks * 32 + quad * 8) ^ cxor;   // swizzled chunk read
      short8 a[FMW], b[2];
#pragma unroll
      for (int f = 0; f < FMW; f++)
        a[f] = *(const short8*)(As[cur] + (wm * FMW * 16 + f * 16 + l15) * 64 + koff);
#pragma unroll
      for (int f = 0; f < 2; f++)
        b[f] = *(const short8*)(Bs[cur] + (wn * 32 + f * 16 + l15) * 64 + koff);
#pragma unroll
      for (int fm = 0; fm < FMW; fm++)
#pragma unroll
        for (int fn = 0; fn < 2; fn++)
          acc[fm][fn] = __builtin_amdgcn_mfma_f32_16x16x32_bf16(a[fm], b[fn], acc[fm][fn], 0, 0, 0);
    }
    __syncthreads();
  }

  // C/D layout (verified): col = lane&15, row = (lane>>4)*4 + reg
  u16* Cb = Cm + (size_t)bz * M * N;
#pragma unroll
  for (int fm = 0; fm < FMW; fm++)
#pragma unroll
    for (int fn = 0; fn < 2; fn++)
#pragma unroll
      for (int r = 0; r < 4; r++) {
        int row = m0 + wm * FMW * 16 + fm * 16 + quad * 4 + r;
        int col = n0 + wn * 32 + fn * 16 + l15;
        Cb[(size_t)row * N + col] = f32_to_bf16(scale * acc[fm][fn][r]);
      }
}

// ---------------------------------------------------------------------------
// Softmax over 1024-wide rows of EP (bf16), in place. One wave per row,
// 4 rows per block; pure __shfl_xor reduction, no LDS, no barriers.
// ---------------------------------------------------------------------------
__global__ __launch_bounds__(256) void softmax_kernel(u16* __restrict__ EP)
{
  const int r = (blockIdx.x << 2) + (threadIdx.x >> 6);   // 0..8191
  const int lane = threadIdx.x & 63;
  u16* row = EP + (size_t)r * 1024;
  const uint4* rp = (const uint4*)row;

  uint4 v0 = rp[lane * 2];
  uint4 v1 = rp[lane * 2 + 1];
  const u32 wds[8] = {v0.x, v0.y, v0.z, v0.w, v1.x, v1.y, v1.z, v1.w};
  float e[16];
#pragma unroll
  for (int i = 0; i < 8; i++) {
    e[2 * i]     = bf16_to_f32((u16)wds[i]);
    e[2 * i + 1] = bf16_to_f32((u16)(wds[i] >> 16));
  }

  float mx = e[0];
#pragma unroll
  for (int i = 1; i < 16; i++) mx = fmaxf(mx, e[i]);
#pragma unroll
  for (int off = 32; off > 0; off >>= 1) mx = fmaxf(mx, __shfl_xor(mx, off));

  float s = 0.f;
#pragma unroll
  for (int i = 0; i < 16; i++) { e[i] = __expf(e[i] - mx); s += e[i]; }
#pragma unroll
  for (int off = 32; off > 0; off >>= 1) s += __shfl_xor(s, off);

  const float inv = 1.0f / s;
  uint4 o0, o1;
  o0.x = pack2(e[0] * inv,  e[1] * inv);
  o0.y = pack2(e[2] * inv,  e[3] * inv);
  o0.z = pack2(e[4] * inv,  e[5] * inv);
  o0.w = pack2(e[6] * inv,  e[7] * inv);
  o1.x = pack2(e[8] * inv,  e[9] * inv);
  o1.y = pack2(e[10] * inv, e[11] * inv);
  o1.z = pack2(e[12] * inv, e[13] * inv);
  o1.w = pack2(e[14] * inv, e[15] * inv);
  ((uint4*)row)[lane * 2]     = o0;
  ((uint4*)row)[lane * 2 + 1] = o1;
}

// ---------------------------------------------------------------------------
// K5: out = gamma*(Wo . OT + bo) + x
// v3: 2048 blocks (8/CU, 32 waves/CU): o-loop split in 2 halves across
// blocks (OT re-read +8MB, ~3% traffic) and 2 px/thread (float2).
// ---------------------------------------------------------------------------
__global__ __launch_bounds__(256) void out_kernel(
    const float* __restrict__ x, const u16* __restrict__ OT,
    const float* __restrict__ Wo, const float* __restrict__ bo,
    const float* __restrict__ gammap, float* __restrict__ out)
{
  const int gb = blockIdx.x;                       // 0..2047
  const int osel = gb & 1;
  const int q2 = (gb >> 1) * 256 + threadIdx.x;    // pixel-pair id, 0..262143
  const int b = q2 >> 15;
  const int rem = (q2 & 32767) * 2;                // pixel offset, even
  const float gmv = gammap[0];

  const u16* otb = OT + (size_t)b * 524288;
  const int m0 = rem & 511;
  const int nbase = rem >> 9;
  float oc[8][2];
#pragma unroll
  for (int cq = 0; cq < 8; cq++) {
    ushort2 hv = *(const ushort2*)(otb + (size_t)(cq * 128 + nbase) * 512 + m0);
    oc[cq][0] = bf16_to_f32(hv.x);
    oc[cq][1] = bf16_to_f32(hv.y);
  }

  const size_t obase = (size_t)b * 4194304 + rem + (size_t)osel * 32 * 65536;
  const float* xb = x + obase;
  float* ob = out + obase;
  const int o0 = osel * 32;
#pragma unroll 4
  for (int oo = 0; oo < 32; oo++) {
    const int o = o0 + oo;
    const float2 xv = *(const float2*)(xb + (size_t)oo * 65536);
    const float bv = bo[o];
    float a0 = bv, a1 = bv;
#pragma unroll
    for (int cq = 0; cq < 8; cq++) {
      const float wv = Wo[o * 8 + cq];
      a0 = fmaf(wv, oc[cq][0], a0);
      a1 = fmaf(wv, oc[cq][1], a1);
    }
    float2 rv;
    rv.x = fmaf(gmv, a0, xv.x);
    rv.y = fmaf(gmv, a1, xv.y);
    *(float2*)(ob + (size_t)oo * 65536) = rv;
  }
}

// ---------------------------------------------------------------------------
extern "C" void kernel_launch(void* const* d_in, const int* in_sizes, int n_in,
                              void* d_out, int out_size, void* d_ws, size_t ws_size,
                              hipStream_t stream) {
  const float* x  = (const float*)d_in[0];
  const float* Wq = (const float*)d_in[1];
  const float* bq = (const float*)d_in[2];
  const float* Wk = (const float*)d_in[3];
  const float* bk = (const float*)d_in[4];
  const float* Wv = (const float*)d_in[5];
  const float* bv = (const float*)d_in[6];
  const float* Wo = (const float*)d_in[7];
  const float* bo = (const float*)d_in[8];
  const float* gm = (const float*)d_in[9];
  float* out = (float*)d_out;

  // workspace carve: qt | kt | v | EP ; OT reuses qt (dead after gemm1)
  u16* qt = (u16*)d_ws;            // 8*1024*512
  u16* kt = qt + 4194304;
  u16* vm = kt + 4194304;
  u16* EP = vm + 4194304;          // 8*1024*1024
  u16* OT = qt;                    // reuse

  qkv_kernel<<<dim3(32, 2, 8), 512, 0, stream>>>(x, Wq, bq, Wk, bk, Wv, bv, qt, kt, vm);
  // E = qt * kt^T / 32   (M=1024, N=1024, K=512); batch on x for XCD-L2 locality
  gemm_nt<4><<<dim3(8, 8, 8), 512, 0, stream>>>(qt, kt, EP, 1024, 1024, 512, 0.03125f);
  softmax_kernel<<<2048, 256, 0, stream>>>(EP);
  // OT[j][m] = P * v^T   (M=1024, N=512, K=1024)
  gemm_nt<2><<<dim3(8, 4, 16), 512, 0, stream>>>(EP, vm, OT, 1024, 512, 1024, 1.0f);
  out_kernel<<<2048, 256, 0, stream>>>(x, OT, Wo, bo, gm, out);
}